// Round 16
// baseline (688.406 us; speedup 1.0000x reference)
//
#include <hip/hip_runtime.h>
#include <math.h>

// ============================================================================
// StableHolographicLayer — round 16: round-15 champion (679us) with GEMM1
// switched to n-inner (A-fragments read ONCE per ks; the n-split existed only
// for the round-7/8 dual-accumulator spill, gone since single-acc).
// acc2 init deferred until after GEMM1-h1 -> a1[2][2] (32) and acc2 (16)
// never co-live: peak acc stays 32 (round-11's failed n-inner had 48).
// Numerics: single-acc fp16 split, x64 weight pre-scale (absmax 0.00390625,
// bit-identical k-order). 4 barriers/module, 48KB LDS, waves_per_eu(3,4).
// ============================================================================

#define NMOD 8

typedef float    f32x4  __attribute__((ext_vector_type(4)));
typedef _Float16 f16x8  __attribute__((ext_vector_type(8)));
typedef _Float16 f16x2  __attribute__((ext_vector_type(2)));
typedef __fp16   fp16v2 __attribute__((ext_vector_type(2)));

union PKC { fp16v2 raw; f16x2 v; };
static __device__ __forceinline__ f16x2 pkrtz(float a, float b) {
    PKC u; u.raw = __builtin_amdgcn_cvt_pkrtz(a, b); return u.v;
}

union U16V { f16x8 v; f16x2 p[4]; };

// LDS byte offsets (total 48 KB)
#define AHI_OFF  0u        // [32][128] f16 hi, swizzled   (8 KB)
#define ALO_OFF  8192u     // [32][128] f16 lo             (8 KB)
#define H0HI_OFF 16384u    // [32][128] f16 hi (half 0)    (8 KB)
#define H0LO_OFF 24576u    // [32][128] f16 lo (half 0)    (8 KB)
#define H1HI_OFF 32768u    // [32][128] f16 hi (half 1)    (8 KB)
#define H1LO_OFF 40960u    // [32][128] f16 lo (half 1)    (8 KB)
#define ST_OFF   16384u    // f32 [32][128] state buffer overlays H0 (16 KB)

// workspace byte offsets
#define WS_W1 0u          // [8][2][4][16][64][8] f16 : 1 MiB
#define WS_W2 1048576u    // [8][2][8][8][64][8]  f16 : 1 MiB
#define WS_CW 2097152u    // [2][4][8][64][8]     f16 : 64 KiB
#define WS_FV 2162688u    // [8][128] f32 : 4 KiB

#define WSCALE 64.0f
#define INV64  0.015625f

static __device__ __forceinline__ float gelu_fast(float y) {
    // 0.5*y*(1+erf(y/sqrt(2))), erf via A&S 7.1.26 (|err| < 1.5e-7)
    float z  = y * 0.70710678118654752440f;
    float az = fabsf(z);
    float t  = __builtin_amdgcn_rcpf(1.0f + 0.3275911f * az);
    float poly = t * (0.254829592f + t * (-0.284496736f + t * (1.421413741f
               + t * (-1.453152027f + t * 1.061405429f))));
    float e  = __expf(-az * az);
    float erfa = 1.0f - poly * e;
    float er = (z < 0.0f) ? -erfa : erfa;
    return 0.5f * y * (1.0f + er);
}

#define MFMA16(a, b, c) __builtin_amdgcn_mfma_f32_16x16x32_f16((a), (b), (c), 0, 0, 0)

// ---------------------------------------------------------------------------
// Setup: convert 64*w1 / 64*w2 / 64*comb_w into fragment-ordered fp16 hi/lo.
// ---------------------------------------------------------------------------
__global__ void setup_weights(const float* __restrict__ w1,
                              const float* __restrict__ w2,
                              const float* __restrict__ cw,
                              _Float16* __restrict__ w1cv,
                              _Float16* __restrict__ w2cv,
                              _Float16* __restrict__ cwcv)
{
    unsigned id = blockIdx.x * blockDim.x + threadIdx.x;
    if (id < 262144u) {                       // w1: [8][128][256]
        unsigned i8 = id & 7u;
        unsigned l  = (id >> 3) & 63u;
        unsigned nt = (id >> 9) & 15u;
        unsigned ks = (id >> 13) & 3u;
        unsigned mo = id >> 15;
        unsigned k = ks * 32u + ((l >> 4) << 3) + i8;
        unsigned c = nt * 16u + (l & 15u);
        float v = w1[(mo * 128u + k) * 256u + c] * WSCALE;
        _Float16 hh = (_Float16)v;
        _Float16 ll = (_Float16)(v - (float)hh);
        w1cv[((((mo * 2u + 0u) * 4u + ks) * 16u + nt) * 64u + l) * 8u + i8] = hh;
        w1cv[((((mo * 2u + 1u) * 4u + ks) * 16u + nt) * 64u + l) * 8u + i8] = ll;
    } else if (id < 524288u) {                // w2: [8][256][128]
        unsigned id2 = id - 262144u;
        unsigned i8 = id2 & 7u;
        unsigned l  = (id2 >> 3) & 63u;
        unsigned nt = (id2 >> 9) & 7u;
        unsigned kt = (id2 >> 12) & 7u;
        unsigned mo = id2 >> 15;
        unsigned k = kt * 32u + ((l >> 4) << 3) + i8;
        unsigned c = nt * 16u + (l & 15u);
        float v = w2[(mo * 256u + k) * 128u + c] * WSCALE;
        _Float16 hh = (_Float16)v;
        _Float16 ll = (_Float16)(v - (float)hh);
        w2cv[((((mo * 2u + 0u) * 8u + kt) * 8u + nt) * 64u + l) * 8u + i8] = hh;
        w2cv[((((mo * 2u + 1u) * 8u + kt) * 8u + nt) * 64u + l) * 8u + i8] = ll;
    } else if (id < 540672u) {                // comb_w: [128][128]
        unsigned id3 = id - 524288u;
        unsigned i8 = id3 & 7u;
        unsigned l  = (id3 >> 3) & 63u;
        unsigned nt = (id3 >> 9) & 7u;
        unsigned ks = id3 >> 12;
        unsigned k = ks * 32u + ((l >> 4) << 3) + i8;
        unsigned c = nt * 16u + (l & 15u);
        float v = cw[k * 128u + c] * WSCALE;
        _Float16 hh = (_Float16)v;
        _Float16 ll = (_Float16)(v - (float)hh);
        cwcv[(((0u * 4u + ks) * 8u + nt) * 64u + l) * 8u + i8] = hh;
        cwcv[(((1u * 4u + ks) * 8u + nt) * 64u + l) * 8u + i8] = ll;
    }
}

__global__ void setup_fv(const float* __restrict__ fb,
                         const float* __restrict__ sm,
                         float* __restrict__ fv)
{
    unsigned tid = blockIdx.x * blockDim.x + threadIdx.x;   // 0..1023
    unsigned i = tid >> 7, d = tid & 127u;
    float px = (float)((i >> 2) & 1u);
    float py = (float)((i >> 1) & 1u);
    float pz = (float)(i & 1u);
    float dot = px * sm[(i * 3u + 0u) * 128u + d]
              + py * sm[(i * 3u + 1u) * 128u + d]
              + pz * sm[(i * 3u + 2u) * 128u + d];
    float pw = 1.0f / (1.0f + expf(-dot));
    float mb = 0.0f;
    #pragma unroll
    for (int k = 0; k < 8; ++k) mb += fb[(i * 8u + (unsigned)k) * 128u + d];
    mb *= 0.125f;
    fv[i * 128u + d] = pw * mb;
}

// ---------------------------------------------------------------------------
// Main kernel. grid = 4096 x 256, 32 rows/block, 48 KB LDS, 3 blocks/CU.
// ---------------------------------------------------------------------------
__global__ __launch_bounds__(256)
__attribute__((amdgpu_waves_per_eu(3, 4)))
void holo_main(const float* __restrict__ x,
               const float* __restrict__ ln1_g, const float* __restrict__ ln1_b,
               const float* __restrict__ bias1, const float* __restrict__ bias2,
               const float* __restrict__ ln2_g, const float* __restrict__ ln2_b,
               const float* __restrict__ cln_g, const float* __restrict__ cln_b,
               const float* __restrict__ comb_b,
               const _Float16* __restrict__ w1cv,
               const _Float16* __restrict__ w2cv,
               const _Float16* __restrict__ cwcv,
               const float* __restrict__ fv,
               float* __restrict__ out)
{
    __shared__ __align__(16) unsigned char lds[49152];

    const unsigned t  = threadIdx.x;
    const unsigned r  = t >> 3;        // LN-phase row 0..31
    const unsigned q8 = t & 7u;        // LN-phase col group (16 cols)
    const unsigned w  = t >> 6;        // wave 0..3
    const unsigned l  = t & 63u;       // lane
    const unsigned lr = l & 15u;
    const unsigned lg = l >> 4;
    const unsigned drow = lg * 4u;     // D-fragment base row
    const unsigned row0 = blockIdx.x * 32u;

    const f32x4 FZ = {0.f, 0.f, 0.f, 0.f};

    float Sv[16], xv[16];
    #pragma unroll
    for (int j = 0; j < 16; ++j) Sv[j] = 0.f;
    {
        const float4* xp = (const float4*)(x + (row0 + r) * 128u + q8 * 16u);
        #pragma unroll
        for (int u = 0; u < 4; ++u) {
            float4 v = xp[u];
            xv[4*u+0] = v.x; xv[4*u+1] = v.y; xv[4*u+2] = v.z; xv[4*u+3] = v.w;
        }
    }

    for (int mod = 0; mod < NMOD; ++mod) {
        const unsigned mo = (unsigned)mod;
        // ---------- phase 1: LN1(x + fv + coef*S) -> A planes ----------
        {
            const float coef = (mod == 0) ? 0.0f : (0.1f / (float)mod);
            float h[16];
            const float4* fvp = (const float4*)(fv + mo * 128u + q8 * 16u);
            #pragma unroll
            for (int u = 0; u < 4; ++u) {
                float4 f4 = fvp[u];
                h[4*u+0] = xv[4*u+0] + f4.x + coef * Sv[4*u+0];
                h[4*u+1] = xv[4*u+1] + f4.y + coef * Sv[4*u+1];
                h[4*u+2] = xv[4*u+2] + f4.z + coef * Sv[4*u+2];
                h[4*u+3] = xv[4*u+3] + f4.w + coef * Sv[4*u+3];
            }
            float s = 0.f;
            #pragma unroll
            for (int j = 0; j < 16; ++j) s += h[j];
            s += __shfl_xor(s, 1); s += __shfl_xor(s, 2); s += __shfl_xor(s, 4);
            const float mean = s * (1.0f / 128.0f);
            float ss = 0.f;
            #pragma unroll
            for (int j = 0; j < 16; ++j) { float d = h[j] - mean; ss += d * d; }
            ss += __shfl_xor(ss, 1); ss += __shfl_xor(ss, 2); ss += __shfl_xor(ss, 4);
            const float var  = ss * (1.0f / 128.0f);
            const float rstd = 1.0f / sqrtf(var + 1e-5f);
            const float4* gp = (const float4*)(ln1_g + mo * 128u + q8 * 16u);
            const float4* bp = (const float4*)(ln1_b + mo * 128u + q8 * 16u);
            #pragma unroll
            for (int e2 = 0; e2 < 2; ++e2) {
                U16V vh, vl;
                #pragma unroll
                for (int u = 0; u < 2; ++u) {
                    float4 g4 = gp[e2*2+u], b4 = bp[e2*2+u];
                    int e0 = e2*8 + u*4;
                    float n0 = (h[e0+0] - mean) * rstd * g4.x + b4.x;
                    float n1 = (h[e0+1] - mean) * rstd * g4.y + b4.y;
                    float n2 = (h[e0+2] - mean) * rstd * g4.z + b4.z;
                    float n3 = (h[e0+3] - mean) * rstd * g4.w + b4.w;
                    f16x2 h01 = pkrtz(n0, n1);
                    f16x2 h23 = pkrtz(n2, n3);
                    f16x2 l01 = pkrtz(n0 - (float)h01[0], n1 - (float)h01[1]);
                    f16x2 l23 = pkrtz(n2 - (float)h23[0], n3 - (float)h23[1]);
                    vh.p[u*2+0] = h01; vh.p[u*2+1] = h23;
                    vl.p[u*2+0] = l01; vl.p[u*2+1] = l23;
                }
                unsigned off = ((r * 256u + q8 * 32u + (unsigned)e2 * 16u) ^ ((r & 7u) << 4));
                *(f16x8*)(lds + AHI_OFF + off) = vh.v;
                *(f16x8*)(lds + ALO_OFF + off) = vl.v;
            }
        }
        __syncthreads();   // bar1: A ready

        // ---------- phase 2: GEMM1 half0 (n-inner) + GELU -> H0 ----------
        {
            f32x4 a1[2][2];
            #pragma unroll
            for (int m = 0; m < 2; ++m) { a1[m][0] = FZ; a1[m][1] = FZ; }
            #pragma unroll
            for (int ks = 0; ks < 4; ++ks) {
                f16x8 ah[2], al[2];
                #pragma unroll
                for (int m = 0; m < 2; ++m) {
                    unsigned rowA = (unsigned)m * 16u + lr;
                    unsigned off = ((rowA * 256u + (unsigned)ks * 64u + lg * 16u) ^ ((lr & 7u) << 4));
                    ah[m] = *(const f16x8*)(lds + AHI_OFF + off);
                    al[m] = *(const f16x8*)(lds + ALO_OFF + off);
                }
                #pragma unroll
                for (int n = 0; n < 2; ++n) {
                    unsigned ntg = w * 2u + (unsigned)n;
                    const f16x8 bh = *(const f16x8*)(const void*)
                        (w1cv + (((mo * 2u + 0u) * 4u + (unsigned)ks) * 16u + ntg) * 512u + l * 8u);
                    const f16x8 bl = *(const f16x8*)(const void*)
                        (w1cv + (((mo * 2u + 1u) * 4u + (unsigned)ks) * 16u + ntg) * 512u + l * 8u);
                    #pragma unroll
                    for (int m = 0; m < 2; ++m) {
                        a1[m][n] = MFMA16(ah[m], bh, a1[m][n]);
                        a1[m][n] = MFMA16(al[m], bh, a1[m][n]);
                        a1[m][n] = MFMA16(ah[m], bl, a1[m][n]);
                    }
                }
            }
            #pragma unroll
            for (int n = 0; n < 2; ++n) {
                unsigned c128 = w * 32u + (unsigned)n * 16u + lr;
                float bb = bias1[mo * 256u + c128];
                #pragma unroll
                for (int m = 0; m < 2; ++m) {
                    float ge[4];
                    #pragma unroll
                    for (int j = 0; j < 4; ++j)
                        ge[j] = gelu_fast(a1[m][n][j] * INV64 + bb);
                    f16x2 h01 = pkrtz(ge[0], ge[1]);
                    f16x2 h23 = pkrtz(ge[2], ge[3]);
                    f16x2 l01 = pkrtz(ge[0] - (float)h01[0], ge[1] - (float)h01[1]);
                    f16x2 l23 = pkrtz(ge[2] - (float)h23[0], ge[3] - (float)h23[1]);
                    _Float16 hv[4] = {h01[0], h01[1], h23[0], h23[1]};
                    _Float16 lv[4] = {l01[0], l01[1], l23[0], l23[1]};
                    #pragma unroll
                    for (int j = 0; j < 4; ++j) {
                        unsigned rowA = (unsigned)m * 16u + drow + (unsigned)j;
                        unsigned off = ((rowA * 256u + c128 * 2u) ^ ((rowA & 7u) << 4));
                        *(_Float16*)(lds + H0HI_OFF + off) = hv[j];
                        *(_Float16*)(lds + H0LO_OFF + off) = lv[j];
                    }
                }
            }
        }
        __syncthreads();   // bar2: H0 ready

        f32x4 acc2[2][2];

        // ---------- phase 3: GEMM1 half1 (n-inner) + GELU -> H1 ; GEMM2 p0 ----------
        {
            f32x4 a1[2][2];
            #pragma unroll
            for (int m = 0; m < 2; ++m) { a1[m][0] = FZ; a1[m][1] = FZ; }
            #pragma unroll
            for (int ks = 0; ks < 4; ++ks) {
                f16x8 ah[2], al[2];
                #pragma unroll
                for (int m = 0; m < 2; ++m) {
                    unsigned rowA = (unsigned)m * 16u + lr;
                    unsigned off = ((rowA * 256u + (unsigned)ks * 64u + lg * 16u) ^ ((lr & 7u) << 4));
                    ah[m] = *(const f16x8*)(lds + AHI_OFF + off);
                    al[m] = *(const f16x8*)(lds + ALO_OFF + off);
                }
                #pragma unroll
                for (int n = 0; n < 2; ++n) {
                    unsigned ntg = 8u + w * 2u + (unsigned)n;
                    const f16x8 bh = *(const f16x8*)(const void*)
                        (w1cv + (((mo * 2u + 0u) * 4u + (unsigned)ks) * 16u + ntg) * 512u + l * 8u);
                    const f16x8 bl = *(const f16x8*)(const void*)
                        (w1cv + (((mo * 2u + 1u) * 4u + (unsigned)ks) * 16u + ntg) * 512u + l * 8u);
                    #pragma unroll
                    for (int m = 0; m < 2; ++m) {
                        a1[m][n] = MFMA16(ah[m], bh, a1[m][n]);
                        a1[m][n] = MFMA16(al[m], bh, a1[m][n]);
                        a1[m][n] = MFMA16(ah[m], bl, a1[m][n]);
                    }
                }
            }
            #pragma unroll
            for (int n = 0; n < 2; ++n) {
                unsigned c128 = w * 32u + (unsigned)n * 16u + lr;
                float bb = bias1[mo * 256u + 128u + c128];
                #pragma unroll
                for (int m = 0; m < 2; ++m) {
                    float ge[4];
                    #pragma unroll
                    for (int j = 0; j < 4; ++j)
                        ge[j] = gelu_fast(a1[m][n][j] * INV64 + bb);
                    f16x2 h01 = pkrtz(ge[0], ge[1]);
                    f16x2 h23 = pkrtz(ge[2], ge[3]);
                    f16x2 l01 = pkrtz(ge[0] - (float)h01[0], ge[1] - (float)h01[1]);
                    f16x2 l23 = pkrtz(ge[2] - (float)h23[0], ge[3] - (float)h23[1]);
                    _Float16 hv[4] = {h01[0], h01[1], h23[0], h23[1]};
                    _Float16 lv[4] = {l01[0], l01[1], l23[0], l23[1]};
                    #pragma unroll
                    for (int j = 0; j < 4; ++j) {
                        unsigned rowA = (unsigned)m * 16u + drow + (unsigned)j;
                        unsigned off = ((rowA * 256u + c128 * 2u) ^ ((rowA & 7u) << 4));
                        *(_Float16*)(lds + H1HI_OFF + off) = hv[j];
                        *(_Float16*)(lds + H1LO_OFF + off) = lv[j];
                    }
                }
            }
        }
        // GEMM2 pass0: kt = 0..3, reads H0  (acc2 starts here — a1 is dead)
        #pragma unroll
        for (int m = 0; m < 2; ++m) { acc2[m][0] = FZ; acc2[m][1] = FZ; }
        #pragma unroll
        for (int ks = 0; ks < 4; ++ks) {
            unsigned kt = (unsigned)ks;
            f16x8 ah2[2], al2[2];
            #pragma unroll
            for (int m = 0; m < 2; ++m) {
                unsigned rowA = (unsigned)m * 16u + lr;
                unsigned off = ((rowA * 256u + (unsigned)ks * 64u + lg * 16u) ^ ((lr & 7u) << 4));
                ah2[m] = *(const f16x8*)(lds + H0HI_OFF + off);
                al2[m] = *(const f16x8*)(lds + H0LO_OFF + off);
            }
            #pragma unroll
            for (int n = 0; n < 2; ++n) {
                unsigned nt2 = w * 2u + (unsigned)n;
                const f16x8 bh = *(const f16x8*)(const void*)
                    (w2cv + (((mo * 2u + 0u) * 8u + kt) * 8u + nt2) * 512u + l * 8u);
                const f16x8 bl = *(const f16x8*)(const void*)
                    (w2cv + (((mo * 2u + 1u) * 8u + kt) * 8u + nt2) * 512u + l * 8u);
                #pragma unroll
                for (int m = 0; m < 2; ++m) {
                    acc2[m][n] = MFMA16(ah2[m], bh, acc2[m][n]);
                    acc2[m][n] = MFMA16(al2[m], bh, acc2[m][n]);
                    acc2[m][n] = MFMA16(ah2[m], bl, acc2[m][n]);
                }
            }
        }
        __syncthreads();   // bar3: H1 ready; all H0 reads done

        // ---------- phase 4: GEMM2 pass1 (H1); state -> H0 overlay ----------
        #pragma unroll
        for (int ks = 0; ks < 4; ++ks) {
            unsigned kt = 4u + (unsigned)ks;
            f16x8 ah2[2], al2[2];
            #pragma unroll
            for (int m = 0; m < 2; ++m) {
                unsigned rowA = (unsigned)m * 16u + lr;
                unsigned off = ((rowA * 256u + (unsigned)ks * 64u + lg * 16u) ^ ((lr & 7u) << 4));
                ah2[m] = *(const f16x8*)(lds + H1HI_OFF + off);
                al2[m] = *(const f16x8*)(lds + H1LO_OFF + off);
            }
            #pragma unroll
            for (int n = 0; n < 2; ++n) {
                unsigned nt2 = w * 2u + (unsigned)n;
                const f16x8 bh = *(const f16x8*)(const void*)
                    (w2cv + (((mo * 2u + 0u) * 8u + kt) * 8u + nt2) * 512u + l * 8u);
                const f16x8 bl = *(const f16x8*)(const void*)
                    (w2cv + (((mo * 2u + 1u) * 8u + kt) * 8u + nt2) * 512u + l * 8u);
                #pragma unroll
                for (int m = 0; m < 2; ++m) {
                    acc2[m][n] = MFMA16(ah2[m], bh, acc2[m][n]);
                    acc2[m][n] = MFMA16(al2[m], bh, acc2[m][n]);
                    acc2[m][n] = MFMA16(ah2[m], bl, acc2[m][n]);
                }
            }
        }
        #pragma unroll
        for (int n = 0; n < 2; ++n) {
            unsigned c = w * 32u + (unsigned)n * 16u + lr;
            float bb = bias2[mo * 128u + c];
            #pragma unroll
            for (int m = 0; m < 2; ++m) {
                #pragma unroll
                for (int j = 0; j < 4; ++j) {
                    unsigned rowA = (unsigned)m * 16u + drow + (unsigned)j;
                    unsigned off = ((rowA * 512u + c * 4u) ^ ((rowA & 7u) << 4));
                    *(float*)(lds + ST_OFF + off) = acc2[m][n][j] * INV64 + bb;
                }
            }
        }
        __syncthreads();   // bar4: state ready

        // ---------- phase 5: LN2 -> S += state (no trailing barrier) ----------
        {
            float h2[16];
            #pragma unroll
            for (int e = 0; e < 4; ++e) {
                unsigned off = ((r * 512u + q8 * 64u + (unsigned)e * 16u) ^ ((r & 7u) << 4));
                float4 v = *(const float4*)(lds + ST_OFF + off);
                h2[4*e+0] = v.x; h2[4*e+1] = v.y; h2[4*e+2] = v.z; h2[4*e+3] = v.w;
            }
            float s = 0.f;
            #pragma unroll
            for (int j = 0; j < 16; ++j) s += h2[j];
            s += __shfl_xor(s, 1); s += __shfl_xor(s, 2); s += __shfl_xor(s, 4);
            const float mean = s * (1.0f / 128.0f);
            float ss = 0.f;
            #pragma unroll
            for (int j = 0; j < 16; ++j) { float d = h2[j] - mean; ss += d * d; }
            ss += __shfl_xor(ss, 1); ss += __shfl_xor(ss, 2); ss += __shfl_xor(ss, 4);
            const float var  = ss * (1.0f / 128.0f);
            const float rstd = 1.0f / sqrtf(var + 1e-5f);
            const float4* gp = (const float4*)(ln2_g + mo * 128u + q8 * 16u);
            const float4* bp = (const float4*)(ln2_b + mo * 128u + q8 * 16u);
            #pragma unroll
            for (int u = 0; u < 4; ++u) {
                float4 g4 = gp[u], b4 = bp[u];
                Sv[4*u+0] += (h2[4*u+0] - mean) * rstd * g4.x + b4.x;
                Sv[4*u+1] += (h2[4*u+1] - mean) * rstd * g4.y + b4.y;
                Sv[4*u+2] += (h2[4*u+2] - mean) * rstd * g4.z + b4.z;
                Sv[4*u+3] += (h2[4*u+3] - mean) * rstd * g4.w + b4.w;
            }
        }
        // next module's bar1 fences state-region reuse (GELU0 writes after it)
    }

    // ------------- final: LN(S/8) -> A planes -------------
    {
        float h[16];
        #pragma unroll
        for (int j = 0; j < 16; ++j) h[j] = Sv[j] * 0.125f;
        float s = 0.f;
        #pragma unroll
        for (int j = 0; j < 16; ++j) s += h[j];
        s += __shfl_xor(s, 1); s += __shfl_xor(s, 2); s += __shfl_xor(s, 4);
        const float mean = s * (1.0f / 128.0f);
        float ss = 0.f;
        #pragma unroll
        for (int j = 0; j < 16; ++j) { float d = h[j] - mean; ss += d * d; }
        ss += __shfl_xor(ss, 1); ss += __shfl_xor(ss, 2); ss += __shfl_xor(ss, 4);
        const float var  = ss * (1.0f / 128.0f);
        const float rstd = 1.0f / sqrtf(var + 1e-5f);
        const float4* gp = (const float4*)(cln_g + q8 * 16u);
        const float4* bp = (const float4*)(cln_b + q8 * 16u);
        #pragma unroll
        for (int e2 = 0; e2 < 2; ++e2) {
            U16V vh, vl;
            #pragma unroll
            for (int u = 0; u < 2; ++u) {
                float4 g4 = gp[e2*2+u], b4 = bp[e2*2+u];
                int e0 = e2*8 + u*4;
                float n0 = (h[e0+0] - mean) * rstd * g4.x + b4.x;
                float n1 = (h[e0+1] - mean) * rstd * g4.y + b4.y;
                float n2 = (h[e0+2] - mean) * rstd * g4.z + b4.z;
                float n3 = (h[e0+3] - mean) * rstd * g4.w + b4.w;
                f16x2 h01 = pkrtz(n0, n1);
                f16x2 h23 = pkrtz(n2, n3);
                f16x2 l01 = pkrtz(n0 - (float)h01[0], n1 - (float)h01[1]);
                f16x2 l23 = pkrtz(n2 - (float)h23[0], n3 - (float)h23[1]);
                vh.p[u*2+0] = h01; vh.p[u*2+1] = h23;
                vl.p[u*2+0] = l01; vl.p[u*2+1] = l23;
            }
            unsigned off = ((r * 256u + q8 * 32u + (unsigned)e2 * 16u) ^ ((r & 7u) << 4));
            *(f16x8*)(lds + AHI_OFF + off) = vh.v;
            *(f16x8*)(lds + ALO_OFF + off) = vl.v;
        }
    }
    __syncthreads();
    // ------------- final GEMM: LN(s) @ comb_w + comb_b -> out -------------
    {
        #pragma unroll
        for (int n = 0; n < 2; ++n) {
            f32x4 a3[2];
            a3[0] = FZ; a3[1] = FZ;
            #pragma unroll
            for (int ks = 0; ks < 4; ++ks) {
                f16x8 ah[2], al[2];
                #pragma unroll
                for (int m = 0; m < 2; ++m) {
                    unsigned rowA = (unsigned)m * 16u + lr;
                    unsigned off = ((rowA * 256u + (unsigned)ks * 64u + lg * 16u) ^ ((lr & 7u) << 4));
                    ah[m] = *(const f16x8*)(lds + AHI_OFF + off);
                    al[m] = *(const f16x8*)(lds + ALO_OFF + off);
                }
                unsigned nt = w * 2u + (unsigned)n;
                const f16x8 bh = *(const f16x8*)(const void*)
                    (cwcv + ((0u * 4u + (unsigned)ks) * 8u + nt) * 512u + l * 8u);
                const f16x8 bl = *(const f16x8*)(const void*)
                    (cwcv + ((1u * 4u + (unsigned)ks) * 8u + nt) * 512u + l * 8u);
                #pragma unroll
                for (int m = 0; m < 2; ++m) {
                    a3[m] = MFMA16(ah[m], bh, a3[m]);
                    a3[m] = MFMA16(al[m], bh, a3[m]);
                    a3[m] = MFMA16(ah[m], bl, a3[m]);
                }
            }
            unsigned col = w * 32u + (unsigned)n * 16u + lr;
            float bb = comb_b[col];
            #pragma unroll
            for (int m = 0; m < 2; ++m) {
                #pragma unroll
                for (int j = 0; j < 4; ++j) {
                    unsigned rowA = (unsigned)m * 16u + drow + (unsigned)j;
                    out[(row0 + rowA) * 128u + col] = a3[m][j] * INV64 + bb;
                }
            }
        }
    }
}

extern "C" void kernel_launch(void* const* d_in, const int* in_sizes, int n_in,
                              void* d_out, int out_size, void* d_ws, size_t ws_size,
                              hipStream_t stream)
{
    const float* x    = (const float*)d_in[0];
    const float* fb   = (const float*)d_in[1];
    const float* sm   = (const float*)d_in[2];
    const float* ln1g = (const float*)d_in[3];
    const float* ln1b = (const float*)d_in[4];
    const float* w1   = (const float*)d_in[5];
    const float* b1   = (const float*)d_in[6];
    const float* w2   = (const float*)d_in[7];
    const float* b2   = (const float*)d_in[8];
    const float* ln2g = (const float*)d_in[9];
    const float* ln2b = (const float*)d_in[10];
    const float* clng = (const float*)d_in[11];
    const float* clnb = (const float*)d_in[12];
    const float* cw   = (const float*)d_in[13];
    const float* cb   = (const float*)d_in[14];
    float* out = (float*)d_out;
    char* ws = (char*)d_ws;
    _Float16* w1cv = (_Float16*)(ws + WS_W1);
    _Float16* w2cv = (_Float16*)(ws + WS_W2);
    _Float16* cwcv = (_Float16*)(ws + WS_CW);
    float*    fvp  = (float*)(ws + WS_FV);

    setup_weights<<<dim3(2112), dim3(256), 0, stream>>>(w1, w2, cw, w1cv, w2cv, cwcv);
    setup_fv<<<dim3(4), dim3(256), 0, stream>>>(fb, sm, fvp);
    holo_main<<<dim3(4096), dim3(256), 0, stream>>>(x, ln1g, ln1b, b1, b2, ln2g, ln2b,
                                                    clng, clnb, cb, w1cv, w2cv, cwcv, fvp, out);
    (void)in_sizes; (void)n_in; (void)out_size; (void)ws_size;
}

// Round 17
// 676.584 us; speedup vs baseline: 1.0175x; 1.0175x over previous
//
#include <hip/hip_runtime.h>
#include <math.h>

// ============================================================================
// StableHolographicLayer — FINAL (= round-15 champion, 679us, absmax 0.0039).
//
// Math per mod i: h = x + fv[i] + (i? 0.1/i*S : 0); h=LN1(h);
//   g=GELU(h@w1+b1); o=g@w2+b2; S += LN2(o).  out = LN(S/8)@comb_w + comb_b.
//
// Numerics: single-accumulator fp16 hi/lo split via x64 weight pre-scale
//   (weight-lo residual fp16-normal; all 3 MFMAs -> one f32 acc at scale 64,
//   epilogue x 1/64). Dropped term ~2^-22 -> absmax 0.0039 (6.5x margin).
// Structure: 32 rows/block, 4 waves, 48KB LDS (A + H0 + H1; f32 state
//   overlays H0), 4 barriers/module via H double-buffer, n-split GEMM1
//   (a1 peak 16 regs), x persisted in registers, pkrtz conversions,
//   A&S rational GELU, two-pass LN, waves_per_eu(3,4) (only spill-free
//   allocator regime: (4,4) pins arch file at 64 regs and spills).
// Memory at floor: FETCH ~64.5MB (x once), WRITE ~65.5MB (out once).
// ============================================================================

#define NMOD 8

typedef float    f32x4  __attribute__((ext_vector_type(4)));
typedef _Float16 f16x8  __attribute__((ext_vector_type(8)));
typedef _Float16 f16x2  __attribute__((ext_vector_type(2)));
typedef __fp16   fp16v2 __attribute__((ext_vector_type(2)));

union PKC { fp16v2 raw; f16x2 v; };
static __device__ __forceinline__ f16x2 pkrtz(float a, float b) {
    PKC u; u.raw = __builtin_amdgcn_cvt_pkrtz(a, b); return u.v;
}

union U16V { f16x8 v; f16x2 p[4]; };

// LDS byte offsets (total 48 KB)
#define AHI_OFF  0u        // [32][128] f16 hi, swizzled   (8 KB)
#define ALO_OFF  8192u     // [32][128] f16 lo             (8 KB)
#define H0HI_OFF 16384u    // [32][128] f16 hi (half 0)    (8 KB)
#define H0LO_OFF 24576u    // [32][128] f16 lo (half 0)    (8 KB)
#define H1HI_OFF 32768u    // [32][128] f16 hi (half 1)    (8 KB)
#define H1LO_OFF 40960u    // [32][128] f16 lo (half 1)    (8 KB)
#define ST_OFF   16384u    // f32 [32][128] state buffer overlays H0 (16 KB)

// workspace byte offsets
#define WS_W1 0u          // [8][2][4][16][64][8] f16 : 1 MiB
#define WS_W2 1048576u    // [8][2][8][8][64][8]  f16 : 1 MiB
#define WS_CW 2097152u    // [2][4][8][64][8]     f16 : 64 KiB
#define WS_FV 2162688u    // [8][128] f32 : 4 KiB

#define WSCALE 64.0f
#define INV64  0.015625f

static __device__ __forceinline__ float gelu_fast(float y) {
    // 0.5*y*(1+erf(y/sqrt(2))), erf via A&S 7.1.26 (|err| < 1.5e-7)
    float z  = y * 0.70710678118654752440f;
    float az = fabsf(z);
    float t  = __builtin_amdgcn_rcpf(1.0f + 0.3275911f * az);
    float poly = t * (0.254829592f + t * (-0.284496736f + t * (1.421413741f
               + t * (-1.453152027f + t * 1.061405429f))));
    float e  = __expf(-az * az);
    float erfa = 1.0f - poly * e;
    float er = (z < 0.0f) ? -erfa : erfa;
    return 0.5f * y * (1.0f + er);
}

#define MFMA16(a, b, c) __builtin_amdgcn_mfma_f32_16x16x32_f16((a), (b), (c), 0, 0, 0)

// ---------------------------------------------------------------------------
// Setup: convert 64*w1 / 64*w2 / 64*comb_w into fragment-ordered fp16 hi/lo.
// ---------------------------------------------------------------------------
__global__ void setup_weights(const float* __restrict__ w1,
                              const float* __restrict__ w2,
                              const float* __restrict__ cw,
                              _Float16* __restrict__ w1cv,
                              _Float16* __restrict__ w2cv,
                              _Float16* __restrict__ cwcv)
{
    unsigned id = blockIdx.x * blockDim.x + threadIdx.x;
    if (id < 262144u) {                       // w1: [8][128][256]
        unsigned i8 = id & 7u;
        unsigned l  = (id >> 3) & 63u;
        unsigned nt = (id >> 9) & 15u;
        unsigned ks = (id >> 13) & 3u;
        unsigned mo = id >> 15;
        unsigned k = ks * 32u + ((l >> 4) << 3) + i8;
        unsigned c = nt * 16u + (l & 15u);
        float v = w1[(mo * 128u + k) * 256u + c] * WSCALE;
        _Float16 hh = (_Float16)v;
        _Float16 ll = (_Float16)(v - (float)hh);
        w1cv[((((mo * 2u + 0u) * 4u + ks) * 16u + nt) * 64u + l) * 8u + i8] = hh;
        w1cv[((((mo * 2u + 1u) * 4u + ks) * 16u + nt) * 64u + l) * 8u + i8] = ll;
    } else if (id < 524288u) {                // w2: [8][256][128]
        unsigned id2 = id - 262144u;
        unsigned i8 = id2 & 7u;
        unsigned l  = (id2 >> 3) & 63u;
        unsigned nt = (id2 >> 9) & 7u;
        unsigned kt = (id2 >> 12) & 7u;
        unsigned mo = id2 >> 15;
        unsigned k = kt * 32u + ((l >> 4) << 3) + i8;
        unsigned c = nt * 16u + (l & 15u);
        float v = w2[(mo * 256u + k) * 128u + c] * WSCALE;
        _Float16 hh = (_Float16)v;
        _Float16 ll = (_Float16)(v - (float)hh);
        w2cv[((((mo * 2u + 0u) * 8u + kt) * 8u + nt) * 64u + l) * 8u + i8] = hh;
        w2cv[((((mo * 2u + 1u) * 8u + kt) * 8u + nt) * 64u + l) * 8u + i8] = ll;
    } else if (id < 540672u) {                // comb_w: [128][128]
        unsigned id3 = id - 524288u;
        unsigned i8 = id3 & 7u;
        unsigned l  = (id3 >> 3) & 63u;
        unsigned nt = (id3 >> 9) & 7u;
        unsigned ks = id3 >> 12;
        unsigned k = ks * 32u + ((l >> 4) << 3) + i8;
        unsigned c = nt * 16u + (l & 15u);
        float v = cw[k * 128u + c] * WSCALE;
        _Float16 hh = (_Float16)v;
        _Float16 ll = (_Float16)(v - (float)hh);
        cwcv[(((0u * 4u + ks) * 8u + nt) * 64u + l) * 8u + i8] = hh;
        cwcv[(((1u * 4u + ks) * 8u + nt) * 64u + l) * 8u + i8] = ll;
    }
}

__global__ void setup_fv(const float* __restrict__ fb,
                         const float* __restrict__ sm,
                         float* __restrict__ fv)
{
    unsigned tid = blockIdx.x * blockDim.x + threadIdx.x;   // 0..1023
    unsigned i = tid >> 7, d = tid & 127u;
    float px = (float)((i >> 2) & 1u);
    float py = (float)((i >> 1) & 1u);
    float pz = (float)(i & 1u);
    float dot = px * sm[(i * 3u + 0u) * 128u + d]
              + py * sm[(i * 3u + 1u) * 128u + d]
              + pz * sm[(i * 3u + 2u) * 128u + d];
    float pw = 1.0f / (1.0f + expf(-dot));
    float mb = 0.0f;
    #pragma unroll
    for (int k = 0; k < 8; ++k) mb += fb[(i * 8u + (unsigned)k) * 128u + d];
    mb *= 0.125f;
    fv[i * 128u + d] = pw * mb;
}

// ---------------------------------------------------------------------------
// Main kernel. grid = 4096 x 256, 32 rows/block, 48 KB LDS, 3 blocks/CU.
// ---------------------------------------------------------------------------
__global__ __launch_bounds__(256)
__attribute__((amdgpu_waves_per_eu(3, 4)))
void holo_main(const float* __restrict__ x,
               const float* __restrict__ ln1_g, const float* __restrict__ ln1_b,
               const float* __restrict__ bias1, const float* __restrict__ bias2,
               const float* __restrict__ ln2_g, const float* __restrict__ ln2_b,
               const float* __restrict__ cln_g, const float* __restrict__ cln_b,
               const float* __restrict__ comb_b,
               const _Float16* __restrict__ w1cv,
               const _Float16* __restrict__ w2cv,
               const _Float16* __restrict__ cwcv,
               const float* __restrict__ fv,
               float* __restrict__ out)
{
    __shared__ __align__(16) unsigned char lds[49152];

    const unsigned t  = threadIdx.x;
    const unsigned r  = t >> 3;        // LN-phase row 0..31
    const unsigned q8 = t & 7u;        // LN-phase col group (16 cols)
    const unsigned w  = t >> 6;        // wave 0..3
    const unsigned l  = t & 63u;       // lane
    const unsigned lr = l & 15u;
    const unsigned lg = l >> 4;
    const unsigned drow = lg * 4u;     // D-fragment base row
    const unsigned row0 = blockIdx.x * 32u;

    const f32x4 FZ = {0.f, 0.f, 0.f, 0.f};

    float Sv[16], xv[16];
    #pragma unroll
    for (int j = 0; j < 16; ++j) Sv[j] = 0.f;
    {
        const float4* xp = (const float4*)(x + (row0 + r) * 128u + q8 * 16u);
        #pragma unroll
        for (int u = 0; u < 4; ++u) {
            float4 v = xp[u];
            xv[4*u+0] = v.x; xv[4*u+1] = v.y; xv[4*u+2] = v.z; xv[4*u+3] = v.w;
        }
    }

    for (int mod = 0; mod < NMOD; ++mod) {
        const unsigned mo = (unsigned)mod;
        // ---------- phase 1: LN1(x + fv + coef*S) -> A planes ----------
        {
            const float coef = (mod == 0) ? 0.0f : (0.1f / (float)mod);
            float h[16];
            const float4* fvp = (const float4*)(fv + mo * 128u + q8 * 16u);
            #pragma unroll
            for (int u = 0; u < 4; ++u) {
                float4 f4 = fvp[u];
                h[4*u+0] = xv[4*u+0] + f4.x + coef * Sv[4*u+0];
                h[4*u+1] = xv[4*u+1] + f4.y + coef * Sv[4*u+1];
                h[4*u+2] = xv[4*u+2] + f4.z + coef * Sv[4*u+2];
                h[4*u+3] = xv[4*u+3] + f4.w + coef * Sv[4*u+3];
            }
            float s = 0.f;
            #pragma unroll
            for (int j = 0; j < 16; ++j) s += h[j];
            s += __shfl_xor(s, 1); s += __shfl_xor(s, 2); s += __shfl_xor(s, 4);
            const float mean = s * (1.0f / 128.0f);
            float ss = 0.f;
            #pragma unroll
            for (int j = 0; j < 16; ++j) { float d = h[j] - mean; ss += d * d; }
            ss += __shfl_xor(ss, 1); ss += __shfl_xor(ss, 2); ss += __shfl_xor(ss, 4);
            const float var  = ss * (1.0f / 128.0f);
            const float rstd = 1.0f / sqrtf(var + 1e-5f);
            const float4* gp = (const float4*)(ln1_g + mo * 128u + q8 * 16u);
            const float4* bp = (const float4*)(ln1_b + mo * 128u + q8 * 16u);
            #pragma unroll
            for (int e2 = 0; e2 < 2; ++e2) {
                U16V vh, vl;
                #pragma unroll
                for (int u = 0; u < 2; ++u) {
                    float4 g4 = gp[e2*2+u], b4 = bp[e2*2+u];
                    int e0 = e2*8 + u*4;
                    float n0 = (h[e0+0] - mean) * rstd * g4.x + b4.x;
                    float n1 = (h[e0+1] - mean) * rstd * g4.y + b4.y;
                    float n2 = (h[e0+2] - mean) * rstd * g4.z + b4.z;
                    float n3 = (h[e0+3] - mean) * rstd * g4.w + b4.w;
                    f16x2 h01 = pkrtz(n0, n1);
                    f16x2 h23 = pkrtz(n2, n3);
                    f16x2 l01 = pkrtz(n0 - (float)h01[0], n1 - (float)h01[1]);
                    f16x2 l23 = pkrtz(n2 - (float)h23[0], n3 - (float)h23[1]);
                    vh.p[u*2+0] = h01; vh.p[u*2+1] = h23;
                    vl.p[u*2+0] = l01; vl.p[u*2+1] = l23;
                }
                unsigned off = ((r * 256u + q8 * 32u + (unsigned)e2 * 16u) ^ ((r & 7u) << 4));
                *(f16x8*)(lds + AHI_OFF + off) = vh.v;
                *(f16x8*)(lds + ALO_OFF + off) = vl.v;
            }
        }
        __syncthreads();   // bar1: A ready

        f32x4 acc2[2][2];
        #pragma unroll
        for (int m = 0; m < 2; ++m) { acc2[m][0] = FZ; acc2[m][1] = FZ; }

        // ---------- phase 2: GEMM1 half0 + GELU -> H0 ----------
        #pragma unroll
        for (int n = 0; n < 2; ++n) {
            f32x4 a1[2];
            a1[0] = FZ; a1[1] = FZ;
            #pragma unroll
            for (int ks = 0; ks < 4; ++ks) {
                f16x8 ah[2], al[2];
                #pragma unroll
                for (int m = 0; m < 2; ++m) {
                    unsigned rowA = (unsigned)m * 16u + lr;
                    unsigned off = ((rowA * 256u + (unsigned)ks * 64u + lg * 16u) ^ ((lr & 7u) << 4));
                    ah[m] = *(const f16x8*)(lds + AHI_OFF + off);
                    al[m] = *(const f16x8*)(lds + ALO_OFF + off);
                }
                unsigned ntg = w * 2u + (unsigned)n;
                const f16x8 bh = *(const f16x8*)(const void*)
                    (w1cv + (((mo * 2u + 0u) * 4u + (unsigned)ks) * 16u + ntg) * 512u + l * 8u);
                const f16x8 bl = *(const f16x8*)(const void*)
                    (w1cv + (((mo * 2u + 1u) * 4u + (unsigned)ks) * 16u + ntg) * 512u + l * 8u);
                #pragma unroll
                for (int m = 0; m < 2; ++m) {
                    a1[m] = MFMA16(ah[m], bh, a1[m]);
                    a1[m] = MFMA16(al[m], bh, a1[m]);
                    a1[m] = MFMA16(ah[m], bl, a1[m]);
                }
            }
            unsigned c128 = w * 32u + (unsigned)n * 16u + lr;
            float bb = bias1[mo * 256u + c128];
            #pragma unroll
            for (int m = 0; m < 2; ++m) {
                float ge[4];
                #pragma unroll
                for (int j = 0; j < 4; ++j)
                    ge[j] = gelu_fast(a1[m][j] * INV64 + bb);
                f16x2 h01 = pkrtz(ge[0], ge[1]);
                f16x2 h23 = pkrtz(ge[2], ge[3]);
                f16x2 l01 = pkrtz(ge[0] - (float)h01[0], ge[1] - (float)h01[1]);
                f16x2 l23 = pkrtz(ge[2] - (float)h23[0], ge[3] - (float)h23[1]);
                _Float16 hv[4] = {h01[0], h01[1], h23[0], h23[1]};
                _Float16 lv[4] = {l01[0], l01[1], l23[0], l23[1]};
                #pragma unroll
                for (int j = 0; j < 4; ++j) {
                    unsigned rowA = (unsigned)m * 16u + drow + (unsigned)j;
                    unsigned off = ((rowA * 256u + c128 * 2u) ^ ((rowA & 7u) << 4));
                    *(_Float16*)(lds + H0HI_OFF + off) = hv[j];
                    *(_Float16*)(lds + H0LO_OFF + off) = lv[j];
                }
            }
        }
        __syncthreads();   // bar2: H0 ready

        // ---------- phase 3: GEMM1 half1 + GELU -> H1 ; GEMM2 pass0 (H0) ----------
        #pragma unroll
        for (int n = 0; n < 2; ++n) {
            f32x4 a1[2];
            a1[0] = FZ; a1[1] = FZ;
            #pragma unroll
            for (int ks = 0; ks < 4; ++ks) {
                f16x8 ah[2], al[2];
                #pragma unroll
                for (int m = 0; m < 2; ++m) {
                    unsigned rowA = (unsigned)m * 16u + lr;
                    unsigned off = ((rowA * 256u + (unsigned)ks * 64u + lg * 16u) ^ ((lr & 7u) << 4));
                    ah[m] = *(const f16x8*)(lds + AHI_OFF + off);
                    al[m] = *(const f16x8*)(lds + ALO_OFF + off);
                }
                unsigned ntg = 8u + w * 2u + (unsigned)n;
                const f16x8 bh = *(const f16x8*)(const void*)
                    (w1cv + (((mo * 2u + 0u) * 4u + (unsigned)ks) * 16u + ntg) * 512u + l * 8u);
                const f16x8 bl = *(const f16x8*)(const void*)
                    (w1cv + (((mo * 2u + 1u) * 4u + (unsigned)ks) * 16u + ntg) * 512u + l * 8u);
                #pragma unroll
                for (int m = 0; m < 2; ++m) {
                    a1[m] = MFMA16(ah[m], bh, a1[m]);
                    a1[m] = MFMA16(al[m], bh, a1[m]);
                    a1[m] = MFMA16(ah[m], bl, a1[m]);
                }
            }
            unsigned c128 = w * 32u + (unsigned)n * 16u + lr;
            float bb = bias1[mo * 256u + 128u + c128];
            #pragma unroll
            for (int m = 0; m < 2; ++m) {
                float ge[4];
                #pragma unroll
                for (int j = 0; j < 4; ++j)
                    ge[j] = gelu_fast(a1[m][j] * INV64 + bb);
                f16x2 h01 = pkrtz(ge[0], ge[1]);
                f16x2 h23 = pkrtz(ge[2], ge[3]);
                f16x2 l01 = pkrtz(ge[0] - (float)h01[0], ge[1] - (float)h01[1]);
                f16x2 l23 = pkrtz(ge[2] - (float)h23[0], ge[3] - (float)h23[1]);
                _Float16 hv[4] = {h01[0], h01[1], h23[0], h23[1]};
                _Float16 lv[4] = {l01[0], l01[1], l23[0], l23[1]};
                #pragma unroll
                for (int j = 0; j < 4; ++j) {
                    unsigned rowA = (unsigned)m * 16u + drow + (unsigned)j;
                    unsigned off = ((rowA * 256u + c128 * 2u) ^ ((rowA & 7u) << 4));
                    *(_Float16*)(lds + H1HI_OFF + off) = hv[j];
                    *(_Float16*)(lds + H1LO_OFF + off) = lv[j];
                }
            }
        }
        // GEMM2 pass0: kt = 0..3, reads H0
        #pragma unroll
        for (int ks = 0; ks < 4; ++ks) {
            unsigned kt = (unsigned)ks;
            f16x8 ah2[2], al2[2];
            #pragma unroll
            for (int m = 0; m < 2; ++m) {
                unsigned rowA = (unsigned)m * 16u + lr;
                unsigned off = ((rowA * 256u + (unsigned)ks * 64u + lg * 16u) ^ ((lr & 7u) << 4));
                ah2[m] = *(const f16x8*)(lds + H0HI_OFF + off);
                al2[m] = *(const f16x8*)(lds + H0LO_OFF + off);
            }
            #pragma unroll
            for (int n = 0; n < 2; ++n) {
                unsigned nt2 = w * 2u + (unsigned)n;
                const f16x8 bh = *(const f16x8*)(const void*)
                    (w2cv + (((mo * 2u + 0u) * 8u + kt) * 8u + nt2) * 512u + l * 8u);
                const f16x8 bl = *(const f16x8*)(const void*)
                    (w2cv + (((mo * 2u + 1u) * 8u + kt) * 8u + nt2) * 512u + l * 8u);
                #pragma unroll
                for (int m = 0; m < 2; ++m) {
                    acc2[m][n] = MFMA16(ah2[m], bh, acc2[m][n]);
                    acc2[m][n] = MFMA16(al2[m], bh, acc2[m][n]);
                    acc2[m][n] = MFMA16(ah2[m], bl, acc2[m][n]);
                }
            }
        }
        __syncthreads();   // bar3: H1 ready; all H0 reads done

        // ---------- phase 4: GEMM2 pass1 (H1); state -> H0 overlay ----------
        #pragma unroll
        for (int ks = 0; ks < 4; ++ks) {
            unsigned kt = 4u + (unsigned)ks;
            f16x8 ah2[2], al2[2];
            #pragma unroll
            for (int m = 0; m < 2; ++m) {
                unsigned rowA = (unsigned)m * 16u + lr;
                unsigned off = ((rowA * 256u + (unsigned)ks * 64u + lg * 16u) ^ ((lr & 7u) << 4));
                ah2[m] = *(const f16x8*)(lds + H1HI_OFF + off);
                al2[m] = *(const f16x8*)(lds + H1LO_OFF + off);
            }
            #pragma unroll
            for (int n = 0; n < 2; ++n) {
                unsigned nt2 = w * 2u + (unsigned)n;
                const f16x8 bh = *(const f16x8*)(const void*)
                    (w2cv + (((mo * 2u + 0u) * 8u + kt) * 8u + nt2) * 512u + l * 8u);
                const f16x8 bl = *(const f16x8*)(const void*)
                    (w2cv + (((mo * 2u + 1u) * 8u + kt) * 8u + nt2) * 512u + l * 8u);
                #pragma unroll
                for (int m = 0; m < 2; ++m) {
                    acc2[m][n] = MFMA16(ah2[m], bh, acc2[m][n]);
                    acc2[m][n] = MFMA16(al2[m], bh, acc2[m][n]);
                    acc2[m][n] = MFMA16(ah2[m], bl, acc2[m][n]);
                }
            }
        }
        #pragma unroll
        for (int n = 0; n < 2; ++n) {
            unsigned c = w * 32u + (unsigned)n * 16u + lr;
            float bb = bias2[mo * 128u + c];
            #pragma unroll
            for (int m = 0; m < 2; ++m) {
                #pragma unroll
                for (int j = 0; j < 4; ++j) {
                    unsigned rowA = (unsigned)m * 16u + drow + (unsigned)j;
                    unsigned off = ((rowA * 512u + c * 4u) ^ ((rowA & 7u) << 4));
                    *(float*)(lds + ST_OFF + off) = acc2[m][n][j] * INV64 + bb;
                }
            }
        }
        __syncthreads();   // bar4: state ready

        // ---------- phase 5: LN2 -> S += state (no trailing barrier) ----------
        {
            float h2[16];
            #pragma unroll
            for (int e = 0; e < 4; ++e) {
                unsigned off = ((r * 512u + q8 * 64u + (unsigned)e * 16u) ^ ((r & 7u) << 4));
                float4 v = *(const float4*)(lds + ST_OFF + off);
                h2[4*e+0] = v.x; h2[4*e+1] = v.y; h2[4*e+2] = v.z; h2[4*e+3] = v.w;
            }
            float s = 0.f;
            #pragma unroll
            for (int j = 0; j < 16; ++j) s += h2[j];
            s += __shfl_xor(s, 1); s += __shfl_xor(s, 2); s += __shfl_xor(s, 4);
            const float mean = s * (1.0f / 128.0f);
            float ss = 0.f;
            #pragma unroll
            for (int j = 0; j < 16; ++j) { float d = h2[j] - mean; ss += d * d; }
            ss += __shfl_xor(ss, 1); ss += __shfl_xor(ss, 2); ss += __shfl_xor(ss, 4);
            const float var  = ss * (1.0f / 128.0f);
            const float rstd = 1.0f / sqrtf(var + 1e-5f);
            const float4* gp = (const float4*)(ln2_g + mo * 128u + q8 * 16u);
            const float4* bp = (const float4*)(ln2_b + mo * 128u + q8 * 16u);
            #pragma unroll
            for (int u = 0; u < 4; ++u) {
                float4 g4 = gp[u], b4 = bp[u];
                Sv[4*u+0] += (h2[4*u+0] - mean) * rstd * g4.x + b4.x;
                Sv[4*u+1] += (h2[4*u+1] - mean) * rstd * g4.y + b4.y;
                Sv[4*u+2] += (h2[4*u+2] - mean) * rstd * g4.z + b4.z;
                Sv[4*u+3] += (h2[4*u+3] - mean) * rstd * g4.w + b4.w;
            }
        }
        // next module's bar1 fences state-region reuse (GELU0 writes after it)
    }

    // ------------- final: LN(S/8) -> A planes -------------
    {
        float h[16];
        #pragma unroll
        for (int j = 0; j < 16; ++j) h[j] = Sv[j] * 0.125f;
        float s = 0.f;
        #pragma unroll
        for (int j = 0; j < 16; ++j) s += h[j];
        s += __shfl_xor(s, 1); s += __shfl_xor(s, 2); s += __shfl_xor(s, 4);
        const float mean = s * (1.0f / 128.0f);
        float ss = 0.f;
        #pragma unroll
        for (int j = 0; j < 16; ++j) { float d = h[j] - mean; ss += d * d; }
        ss += __shfl_xor(ss, 1); ss += __shfl_xor(ss, 2); ss += __shfl_xor(ss, 4);
        const float var  = ss * (1.0f / 128.0f);
        const float rstd = 1.0f / sqrtf(var + 1e-5f);
        const float4* gp = (const float4*)(cln_g + q8 * 16u);
        const float4* bp = (const float4*)(cln_b + q8 * 16u);
        #pragma unroll
        for (int e2 = 0; e2 < 2; ++e2) {
            U16V vh, vl;
            #pragma unroll
            for (int u = 0; u < 2; ++u) {
                float4 g4 = gp[e2*2+u], b4 = bp[e2*2+u];
                int e0 = e2*8 + u*4;
                float n0 = (h[e0+0] - mean) * rstd * g4.x + b4.x;
                float n1 = (h[e0+1] - mean) * rstd * g4.y + b4.y;
                float n2 = (h[e0+2] - mean) * rstd * g4.z + b4.z;
                float n3 = (h[e0+3] - mean) * rstd * g4.w + b4.w;
                f16x2 h01 = pkrtz(n0, n1);
                f16x2 h23 = pkrtz(n2, n3);
                f16x2 l01 = pkrtz(n0 - (float)h01[0], n1 - (float)h01[1]);
                f16x2 l23 = pkrtz(n2 - (float)h23[0], n3 - (float)h23[1]);
                vh.p[u*2+0] = h01; vh.p[u*2+1] = h23;
                vl.p[u*2+0] = l01; vl.p[u*2+1] = l23;
            }
            unsigned off = ((r * 256u + q8 * 32u + (unsigned)e2 * 16u) ^ ((r & 7u) << 4));
            *(f16x8*)(lds + AHI_OFF + off) = vh.v;
            *(f16x8*)(lds + ALO_OFF + off) = vl.v;
        }
    }
    __syncthreads();
    // ------------- final GEMM: LN(s) @ comb_w + comb_b -> out -------------
    {
        #pragma unroll
        for (int n = 0; n < 2; ++n) {
            f32x4 a3[2];
            a3[0] = FZ; a3[1] = FZ;
            #pragma unroll
            for (int ks = 0; ks < 4; ++ks) {
                f16x8 ah[2], al[2];
                #pragma unroll
                for (int m = 0; m < 2; ++m) {
                    unsigned rowA = (unsigned)m * 16u + lr;
                    unsigned off = ((rowA * 256u + (unsigned)ks * 64u + lg * 16u) ^ ((lr & 7u) << 4));
                    ah[m] = *(const f16x8*)(lds + AHI_OFF + off);
                    al[m] = *(const f16x8*)(lds + ALO_OFF + off);
                }
                unsigned nt = w * 2u + (unsigned)n;
                const f16x8 bh = *(const f16x8*)(const void*)
                    (cwcv + ((0u * 4u + (unsigned)ks) * 8u + nt) * 512u + l * 8u);
                const f16x8 bl = *(const f16x8*)(const void*)
                    (cwcv + ((1u * 4u + (unsigned)ks) * 8u + nt) * 512u + l * 8u);
                #pragma unroll
                for (int m = 0; m < 2; ++m) {
                    a3[m] = MFMA16(ah[m], bh, a3[m]);
                    a3[m] = MFMA16(al[m], bh, a3[m]);
                    a3[m] = MFMA16(ah[m], bl, a3[m]);
                }
            }
            unsigned col = w * 32u + (unsigned)n * 16u + lr;
            float bb = comb_b[col];
            #pragma unroll
            for (int m = 0; m < 2; ++m) {
                #pragma unroll
                for (int j = 0; j < 4; ++j) {
                    unsigned rowA = (unsigned)m * 16u + drow + (unsigned)j;
                    out[(row0 + rowA) * 128u + col] = a3[m][j] * INV64 + bb;
                }
            }
        }
    }
}

extern "C" void kernel_launch(void* const* d_in, const int* in_sizes, int n_in,
                              void* d_out, int out_size, void* d_ws, size_t ws_size,
                              hipStream_t stream)
{
    const float* x    = (const float*)d_in[0];
    const float* fb   = (const float*)d_in[1];
    const float* sm   = (const float*)d_in[2];
    const float* ln1g = (const float*)d_in[3];
    const float* ln1b = (const float*)d_in[4];
    const float* w1   = (const float*)d_in[5];
    const float* b1   = (const float*)d_in[6];
    const float* w2   = (const float*)d_in[7];
    const float* b2   = (const float*)d_in[8];
    const float* ln2g = (const float*)d_in[9];
    const float* ln2b = (const float*)d_in[10];
    const float* clng = (const float*)d_in[11];
    const float* clnb = (const float*)d_in[12];
    const float* cw   = (const float*)d_in[13];
    const float* cb   = (const float*)d_in[14];
    float* out = (float*)d_out;
    char* ws = (char*)d_ws;
    _Float16* w1cv = (_Float16*)(ws + WS_W1);
    _Float16* w2cv = (_Float16*)(ws + WS_W2);
    _Float16* cwcv = (_Float16*)(ws + WS_CW);
    float*    fvp  = (float*)(ws + WS_FV);

    setup_weights<<<dim3(2112), dim3(256), 0, stream>>>(w1, w2, cw, w1cv, w2cv, cwcv);
    setup_fv<<<dim3(4), dim3(256), 0, stream>>>(fb, sm, fvp);
    holo_main<<<dim3(4096), dim3(256), 0, stream>>>(x, ln1g, ln1b, b1, b2, ln2g, ln2b,
                                                    clng, clnb, cb, w1cv, w2cv, cwcv, fvp, out);
    (void)in_sizes; (void)n_in; (void)out_size; (void)ws_size;
}